// Round 1
// baseline (7147.668 us; speedup 1.0000x reference)
//
#include <hip/hip_runtime.h>

#define NN 50000
#define NE 1000000
#define NG 1000
#define KE 147
#define DH 128

using u16 = unsigned short;

__device__ __forceinline__ float lrelu(float v){ return v >= 0.f ? v : 0.01f*v; }
__device__ __forceinline__ float bf2f(u16 u){ unsigned int x = ((unsigned int)u)<<16; float f; __builtin_memcpy(&f,&x,4); return f; }
__device__ __forceinline__ u16 f2bf(float f){ unsigned int x; __builtin_memcpy(&x,&f,4); x += 0x7fffu + ((x>>16)&1u); return (u16)(x>>16); }

// ---- layer 0: h0 = lrelu(cf @ W^T + b) (bf16 store); agg[end[e]] += h0[e]
__global__ __launch_bounds__(256) void layer0_kernel(
    const float* __restrict__ cf, const float* __restrict__ W,
    const float* __restrict__ b, const int* __restrict__ endi,
    u16* __restrict__ h, float* __restrict__ agg)
{
  __shared__ float Wt[64*132];
  __shared__ float ms[32*KE];
  const int t = threadIdx.x;
  const int e0 = blockIdx.x * 32;
  const int jg = t & 31, eg = t >> 5;
  for (int idx = t; idx < 32*KE; idx += 256)
    ms[idx] = cf[(size_t)e0*KE + idx];
  float acc[4][4] = {};
  for (int c = 0; c < 3; ++c) {
    const int kw = (c == 2) ? (KE - 128) : 64;
    __syncthreads();
    for (int idx = t; idx < 128*64; idx += 256) {
      const int j = idx >> 6, kl = idx & 63;
      if (kl < kw) Wt[kl*132 + j] = W[j*KE + c*64 + kl];
    }
    __syncthreads();
    for (int kl = 0; kl < kw; ++kl) {
      const float4 w = *(const float4*)&Wt[kl*132 + jg*4];
      const int kg = c*64 + kl;
      #pragma unroll
      for (int i = 0; i < 4; ++i) {
        const float mv = ms[(eg*4+i)*KE + kg];
        acc[i][0] += mv*w.x; acc[i][1] += mv*w.y; acc[i][2] += mv*w.z; acc[i][3] += mv*w.w;
      }
    }
  }
  float bj[4];
  #pragma unroll
  for (int c2 = 0; c2 < 4; ++c2) bj[c2] = b[jg*4 + c2];
  #pragma unroll
  for (int i = 0; i < 4; ++i) {
    const int e = e0 + eg*4 + i;
    float v[4];
    #pragma unroll
    for (int c2 = 0; c2 < 4; ++c2) v[c2] = lrelu(acc[i][c2] + bj[c2]);
    ushort4 pk; pk.x=f2bf(v[0]); pk.y=f2bf(v[1]); pk.z=f2bf(v[2]); pk.w=f2bf(v[3]);
    *(ushort4*)&h[(size_t)e*DH + jg*4] = pk;
    float* ap = &agg[(size_t)endi[e]*DH + jg*4];
    atomicAdd(ap+0,v[0]); atomicAdd(ap+1,v[1]); atomicAdd(ap+2,v[2]); atomicAdd(ap+3,v[3]);
  }
}

// ---- layers 1..3: h = lrelu(h + (agg[srt]-h_head[end]) @ W^T + b); scatter into sout[sidx]
__global__ __launch_bounds__(256) void layer_kernel(
    u16* __restrict__ h, const u16* __restrict__ h_head,
    const float* __restrict__ agg_in, const float* __restrict__ W,
    const float* __restrict__ b, const int* __restrict__ srt,
    const int* __restrict__ endi, const int* __restrict__ sidx,
    float* __restrict__ sout)
{
  __shared__ float Wt[64*132];
  __shared__ float ms[32*DH];
  const int t = threadIdx.x;
  const int e0 = blockIdx.x * 32;
  const int jg = t & 31, eg = t >> 5;
  {
    const int k = t & 127;
    for (int p = 0; p < 16; ++p) {
      const int el = p*2 + (t>>7);
      const int e = e0 + el;
      const int s = srt[e], d = endi[e];
      ms[el*DH + k] = agg_in[(size_t)s*DH + k] - bf2f(h_head[(size_t)d*DH + k]);
    }
  }
  float acc[4][4] = {};
  for (int c = 0; c < 2; ++c) {
    __syncthreads();
    for (int idx = t; idx < 128*64; idx += 256) {
      const int j = idx >> 6, kl = idx & 63;
      Wt[kl*132 + j] = W[j*DH + c*64 + kl];
    }
    __syncthreads();
    #pragma unroll 4
    for (int kl = 0; kl < 64; ++kl) {
      const float4 w = *(const float4*)&Wt[kl*132 + jg*4];
      const int kg = c*64 + kl;
      #pragma unroll
      for (int i = 0; i < 4; ++i) {
        const float mv = ms[(eg*4+i)*DH + kg];
        acc[i][0] += mv*w.x; acc[i][1] += mv*w.y; acc[i][2] += mv*w.z; acc[i][3] += mv*w.w;
      }
    }
  }
  float bj[4];
  #pragma unroll
  for (int c2 = 0; c2 < 4; ++c2) bj[c2] = b[jg*4 + c2];
  #pragma unroll
  for (int i = 0; i < 4; ++i) {
    const int e = e0 + eg*4 + i;
    const ushort4 rp = *(const ushort4*)&h[(size_t)e*DH + jg*4];
    float v[4];
    v[0] = lrelu(acc[i][0] + bj[0] + bf2f(rp.x));
    v[1] = lrelu(acc[i][1] + bj[1] + bf2f(rp.y));
    v[2] = lrelu(acc[i][2] + bj[2] + bf2f(rp.z));
    v[3] = lrelu(acc[i][3] + bj[3] + bf2f(rp.w));
    ushort4 pk; pk.x=f2bf(v[0]); pk.y=f2bf(v[1]); pk.z=f2bf(v[2]); pk.w=f2bf(v[3]);
    *(ushort4*)&h[(size_t)e*DH + jg*4] = pk;
    float* ap = &sout[(size_t)sidx[e]*DH + jg*4];
    atomicAdd(ap+0,v[0]); atomicAdd(ap+1,v[1]); atomicAdd(ap+2,v[2]); atomicAdd(ap+3,v[3]);
  }
}

// ---- nodes: atom = lrelu(h_node @ Wmol^T + b); hg[batch[v]] += atom/||atom||
__global__ __launch_bounds__(256) void node_kernel(
    const float* __restrict__ hn, const float* __restrict__ W,
    const float* __restrict__ b, const int* __restrict__ batch,
    float* __restrict__ atom, float* __restrict__ hg)
{
  __shared__ float Wt[64*132];
  __shared__ float ms[32*DH];
  const int t = threadIdx.x;
  const int r0 = blockIdx.x * 32;
  const int jg = t & 31, eg = t >> 5;
  for (int idx = t; idx < 32*DH; idx += 256) {
    const int r = r0 + (idx >> 7);
    ms[idx] = (r < NN) ? hn[(size_t)r*DH + (idx & 127)] : 0.f;
  }
  float acc[4][4] = {};
  for (int c = 0; c < 2; ++c) {
    __syncthreads();
    for (int idx = t; idx < 128*64; idx += 256) {
      const int j = idx >> 6, kl = idx & 63;
      Wt[kl*132 + j] = W[j*DH + c*64 + kl];
    }
    __syncthreads();
    #pragma unroll 4
    for (int kl = 0; kl < 64; ++kl) {
      const float4 w = *(const float4*)&Wt[kl*132 + jg*4];
      const int kg = c*64 + kl;
      #pragma unroll
      for (int i = 0; i < 4; ++i) {
        const float mv = ms[(eg*4+i)*DH + kg];
        acc[i][0] += mv*w.x; acc[i][1] += mv*w.y; acc[i][2] += mv*w.z; acc[i][3] += mv*w.w;
      }
    }
  }
  float bj[4];
  #pragma unroll
  for (int c2 = 0; c2 < 4; ++c2) bj[c2] = b[jg*4 + c2];
  #pragma unroll
  for (int i = 0; i < 4; ++i) {
    const int r = r0 + eg*4 + i;
    float v[4]; float ss = 0.f;
    #pragma unroll
    for (int c2 = 0; c2 < 4; ++c2) { v[c2] = lrelu(acc[i][c2] + bj[c2]); ss += v[c2]*v[c2]; }
    ss += __shfl_xor(ss, 1); ss += __shfl_xor(ss, 2); ss += __shfl_xor(ss, 4);
    ss += __shfl_xor(ss, 8); ss += __shfl_xor(ss, 16);
    if (r < NN) {
      *(float4*)&atom[(size_t)r*DH + jg*4] = make_float4(v[0],v[1],v[2],v[3]);
      const float inv = 1.f / fmaxf(sqrtf(ss), 1e-12f);
      float* gp = &hg[(size_t)batch[r]*DH + jg*4];
      atomicAdd(gp+0, v[0]*inv); atomicAdd(gp+1, v[1]*inv);
      atomicAdd(gp+2, v[2]*inv); atomicAdd(gp+3, v[3]*inv);
    }
  }
}

__global__ __launch_bounds__(64) void out_kernel(
    const float* __restrict__ hg, const float* __restrict__ Wo,
    const float* __restrict__ bo, float* __restrict__ out)
{
  const int g = blockIdx.x, t = threadIdx.x;
  float v = hg[(size_t)g*DH + t]*Wo[t] + hg[(size_t)g*DH + t + 64]*Wo[t+64];
  v += __shfl_xor(v, 32); v += __shfl_xor(v, 16); v += __shfl_xor(v, 8);
  v += __shfl_xor(v, 4);  v += __shfl_xor(v, 2);  v += __shfl_xor(v, 1);
  if (t == 0) out[g] = v + bo[0];
}

extern "C" void kernel_launch(void* const* d_in, const int* in_sizes, int n_in,
                              void* d_out, int out_size, void* d_ws, size_t ws_size,
                              hipStream_t stream)
{
  const float* cf     = (const float*)d_in[1];
  const int*   srt    = (const int*)d_in[2];
  const int*   endi   = (const int*)d_in[3];
  const int*   batch  = (const int*)d_in[5];
  const float* W_init = (const float*)d_in[6];
  const float* b_init = (const float*)d_in[7];
  const float* W_h1   = (const float*)d_in[8];
  const float* b_h1   = (const float*)d_in[9];
  const float* W_mol  = (const float*)d_in[10];
  const float* b_mol  = (const float*)d_in[11];
  const float* W_out  = (const float*)d_in[12];
  const float* b_out  = (const float*)d_in[13];

  float* out  = (float*)d_out;
  float* atom = out + NG;

  char* ws = (char*)d_ws;
  u16*   h      = (u16*)(ws);                  // E*128 bf16   = 256,000,000 B
  u16*   h_head = (u16*)(ws + 256000000);      // 50000*128 bf16 = 12,800,000 B
  float* aggA   = (float*)(ws + 268800000);    // 25,600,000 B
  float* aggB   = (float*)(ws + 294400000);    // 25,600,000 B
  float* hnode  = (float*)(ws + 320000000);    // 25,600,000 B
  float* hg     = (float*)(ws + 345600000);    // 512,000 B

  hipMemsetAsync(aggA, 0, (size_t)NN*DH*4, stream);
  hipMemsetAsync(hnode, 0, (size_t)NN*DH*4, stream);
  hipMemsetAsync(hg, 0, (size_t)NG*DH*4, stream);

  layer0_kernel<<<NE/32, 256, 0, stream>>>(cf, W_init, b_init, endi, h, aggA);

  // layer 1: reads aggA, scatters aggB
  hipMemcpyAsync(h_head, h, (size_t)NN*DH*2, hipMemcpyDeviceToDevice, stream);
  hipMemsetAsync(aggB, 0, (size_t)NN*DH*4, stream);
  layer_kernel<<<NE/32, 256, 0, stream>>>(h, h_head, aggA, W_h1, b_h1, srt, endi, endi, aggB);
  // layer 2: reads aggB, scatters aggA (re-zeroed)
  hipMemcpyAsync(h_head, h, (size_t)NN*DH*2, hipMemcpyDeviceToDevice, stream);
  hipMemsetAsync(aggA, 0, (size_t)NN*DH*4, stream);
  layer_kernel<<<NE/32, 256, 0, stream>>>(h, h_head, aggB, W_h1, b_h1, srt, endi, endi, aggA);
  // layer 3: reads aggA, scatters h3 by srt into h_node
  hipMemcpyAsync(h_head, h, (size_t)NN*DH*2, hipMemcpyDeviceToDevice, stream);
  layer_kernel<<<NE/32, 256, 0, stream>>>(h, h_head, aggA, W_h1, b_h1, srt, endi, srt, hnode);

  node_kernel<<<(NN+31)/32, 256, 0, stream>>>(hnode, W_mol, b_mol, batch, atom, hg);
  out_kernel<<<NG, 64, 0, stream>>>(hg, W_out, b_out, out);
}

// Round 2
// 1870.582 us; speedup vs baseline: 3.8211x; 3.8211x over previous
//
#include <hip/hip_runtime.h>

#define NN 50000
#define NE 1000000
#define NG 1000
#define KE 147
#define DH 128

using u16 = unsigned short;
typedef __attribute__((ext_vector_type(8))) short bf16x8;
typedef __attribute__((ext_vector_type(4))) float f32x4;

__device__ __forceinline__ float lrelu(float v){ return v >= 0.f ? v : 0.01f*v; }
__device__ __forceinline__ float bf2f(u16 u){ unsigned int x = ((unsigned int)u)<<16; float f; __builtin_memcpy(&f,&x,4); return f; }
__device__ __forceinline__ u16 f2bf(float f){ unsigned int x; __builtin_memcpy(&x,&f,4); x += 0x7fffu + ((x>>16)&1u); return (u16)(x>>16); }

// ================= CSR build =================
__global__ __launch_bounds__(256) void hist_kernel(const int* __restrict__ endi, const int* __restrict__ srt,
                                                   int* __restrict__ cntE, int* __restrict__ cntS){
  for (int i = blockIdx.x*256 + threadIdx.x; i < NE; i += gridDim.x*256){
    atomicAdd(&cntE[endi[i]], 1);
    atomicAdd(&cntS[srt[i]], 1);
  }
}

__global__ __launch_bounds__(1024) void scan_kernel(const int* __restrict__ deg, int* __restrict__ off){
  __shared__ int wsum[17];
  const int t = threadIdx.x, lane = t & 63, wv = t >> 6;
  int carry = 0;
  for (int base = 0; base < 50176; base += 1024){
    const int i = base + t;
    int v = (i < NN) ? deg[i] : 0;
    int s = v;
    #pragma unroll
    for (int d = 1; d < 64; d <<= 1){
      int x = __shfl_up(s, d);
      if (lane >= d) s += x;
    }
    if (lane == 63) wsum[wv] = s;
    __syncthreads();
    if (t == 0){
      int run = 0;
      #pragma unroll
      for (int k = 0; k < 16; ++k){ int x = wsum[k]; wsum[k] = run; run += x; }
      wsum[16] = run;
    }
    __syncthreads();
    if (i <= NN) off[i] = carry + wsum[wv] + s - v;   // exclusive scan; off[NN] = total
    carry += wsum[16];
    __syncthreads();
  }
}

__global__ __launch_bounds__(256) void scatter_kernel(const int* __restrict__ endi, const int* __restrict__ srt,
                                                      int* __restrict__ curE, int* __restrict__ curS,
                                                      int* __restrict__ listE, int* __restrict__ listS){
  for (int i = blockIdx.x*256 + threadIdx.x; i < NE; i += gridDim.x*256){
    int p = atomicAdd(&curE[endi[i]], 1); listE[p] = i;
    int q = atomicAdd(&curS[srt[i]], 1);  listS[q] = i;
  }
}

__global__ __launch_bounds__(256) void convertW_kernel(const float* __restrict__ W1, const float* __restrict__ W0,
                                                       u16* __restrict__ Wbf1, u16* __restrict__ Wbf0){
  int i = blockIdx.x*256 + threadIdx.x;
  if (i < 128*128) Wbf1[i] = f2bf(W1[i]);
  if (i < 128*160){
    int j = i/160, k = i - j*160;
    Wbf0[i] = (k < KE) ? f2bf(W0[j*KE + k]) : (u16)0;
  }
}

// ================= segment-sum via CSR gather (one wave per node) =================
__global__ __launch_bounds__(256) void gather_kernel(const u16* __restrict__ h, const int* __restrict__ list,
                                                     const int* __restrict__ off, float* __restrict__ out){
  const int t = threadIdx.x, lane = t & 63, wv = t >> 6;
  const int node = blockIdx.x*4 + wv;
  if (node >= NN) return;
  const int lo = off[node], hi = off[node+1];
  float2 acc = make_float2(0.f, 0.f);
  const int c = lane*2;
  int j = lo;
  for (; j + 4 <= hi; j += 4){
    int e0 = list[j], e1 = list[j+1], e2 = list[j+2], e3 = list[j+3];
    ushort2 p0 = *(const ushort2*)&h[(size_t)e0*DH + c];
    ushort2 p1 = *(const ushort2*)&h[(size_t)e1*DH + c];
    ushort2 p2 = *(const ushort2*)&h[(size_t)e2*DH + c];
    ushort2 p3 = *(const ushort2*)&h[(size_t)e3*DH + c];
    acc.x += bf2f(p0.x)+bf2f(p1.x)+bf2f(p2.x)+bf2f(p3.x);
    acc.y += bf2f(p0.y)+bf2f(p1.y)+bf2f(p2.y)+bf2f(p3.y);
  }
  for (; j < hi; ++j){
    int e = list[j];
    ushort2 p = *(const ushort2*)&h[(size_t)e*DH + c];
    acc.x += bf2f(p.x); acc.y += bf2f(p.y);
  }
  *(float2*)&out[(size_t)node*DH + c] = acc;
}

// ================= layer 0: h = lrelu(cf @ W0^T + b), MFMA, K=160 padded =================
__global__ __launch_bounds__(256) void layer0_mfma(const float* __restrict__ cf, const u16* __restrict__ Wbf0,
                                                   const float* __restrict__ b, u16* __restrict__ h){
  __shared__ u16 Alds[128][168];          // 43 KB, +8 pad -> conflict-free b128 reads
  const int t = threadIdx.x, lane = t & 63, wv = t >> 6;
  const int wr = wv >> 1, wc = wv & 1;
  const long e0 = (long)blockIdx.x * 128;

  bf16x8 bfrag[5][4];                      // B held in registers (W is block-uniform, L2-hot)
  {
    const int jb = (lane & 15), kg = (lane >> 4)*8;
    #pragma unroll
    for (int fc = 0; fc < 4; ++fc)
      #pragma unroll
      for (int ks = 0; ks < 5; ++ks)
        bfrag[ks][fc] = *(const bf16x8*)&Wbf0[(size_t)(wc*64 + fc*16 + jb)*160 + ks*32 + kg];
  }
  if (blockIdx.x < NE/128){
    // full block: contiguous float4 over cf tile (128*147 floats, 16B-aligned base)
    const float4* cf4 = (const float4*)(cf + (size_t)e0*KE);
    for (int idx = t; idx < (128*KE)/4; idx += 256){
      float4 v = cf4[idx];
      int g = idx*4;
      int r0 = g / KE,       c0 = g - r0*KE;
      int r1 = (g+1) / KE,   c1 = (g+1) - r1*KE;
      int r2 = (g+2) / KE,   c2 = (g+2) - r2*KE;
      int r3 = (g+3) / KE,   c3 = (g+3) - r3*KE;
      Alds[r0][c0] = f2bf(v.x); Alds[r1][c1] = f2bf(v.y);
      Alds[r2][c2] = f2bf(v.z); Alds[r3][c3] = f2bf(v.w);
    }
    for (int idx = t; idx < 128*(160-KE); idx += 256){
      int r = idx / 13, c = idx - r*13;
      Alds[r][KE + c] = 0;
    }
  } else {
    // tail block: zero all, then fill valid scalars
    for (int idx = t; idx < 128*168; idx += 256) ((u16*)Alds)[idx] = 0;
    __syncthreads();
    for (int idx = t; idx < 128*KE; idx += 256){
      size_t ge = (size_t)e0*KE + idx;
      if (ge < (size_t)NE*KE){
        int r = idx / KE, c = idx - r*KE;
        Alds[r][c] = f2bf(cf[ge]);
      }
    }
  }
  __syncthreads();

  f32x4 acc[4][4];
  #pragma unroll
  for (int fr = 0; fr < 4; ++fr)
    #pragma unroll
    for (int fc = 0; fc < 4; ++fc){ acc[fr][fc][0]=0.f; acc[fr][fc][1]=0.f; acc[fr][fc][2]=0.f; acc[fr][fc][3]=0.f; }
  const int ar = (lane & 15), akg = (lane >> 4)*8;
  #pragma unroll
  for (int ks = 0; ks < 5; ++ks){
    bf16x8 a[4];
    #pragma unroll
    for (int fr = 0; fr < 4; ++fr)
      a[fr] = *(const bf16x8*)&Alds[wr*64 + fr*16 + ar][ks*32 + akg];
    #pragma unroll
    for (int fr = 0; fr < 4; ++fr)
      #pragma unroll
      for (int fc = 0; fc < 4; ++fc)
        acc[fr][fc] = __builtin_amdgcn_mfma_f32_16x16x32_bf16(a[fr], bfrag[ks][fc], acc[fr][fc], 0, 0, 0);
  }

  float* Clds = (float*)&Alds[0][0];       // reuse as [64][132] f32
  const int cr0 = (lane >> 4)*4, cc = (lane & 15);
  for (int half = 0; half < 2; ++half){
    __syncthreads();
    if (wr == half){
      #pragma unroll
      for (int fr = 0; fr < 4; ++fr)
        #pragma unroll
        for (int fc = 0; fc < 4; ++fc)
          #pragma unroll
          for (int r = 0; r < 4; ++r)
            Clds[(fr*16 + cr0 + r)*132 + wc*64 + fc*16 + cc] = acc[fr][fc][r];
    }
    __syncthreads();
    const int rr = t >> 2, cb = (t & 3)*32;
    const long e = e0 + half*64 + rr;
    if (e < NE){
      u16* hp = &h[(size_t)e*DH + cb];
      #pragma unroll
      for (int c8 = 0; c8 < 4; ++c8){
        float4 c0 = *(const float4*)&Clds[rr*132 + cb + c8*8];
        float4 c1 = *(const float4*)&Clds[rr*132 + cb + c8*8 + 4];
        float4 b0 = *(const float4*)&b[cb + c8*8];
        float4 b1 = *(const float4*)&b[cb + c8*8 + 4];
        ushort4 n0, n1;
        n0.x = f2bf(lrelu(c0.x + b0.x)); n0.y = f2bf(lrelu(c0.y + b0.y));
        n0.z = f2bf(lrelu(c0.z + b0.z)); n0.w = f2bf(lrelu(c0.w + b0.w));
        n1.x = f2bf(lrelu(c1.x + b1.x)); n1.y = f2bf(lrelu(c1.y + b1.y));
        n1.z = f2bf(lrelu(c1.z + b1.z)); n1.w = f2bf(lrelu(c1.w + b1.w));
        *(ushort4*)&hp[c8*8] = n0; *(ushort4*)&hp[c8*8+4] = n1;
      }
    }
  }
}

// ================= layers 1..3: h = lrelu(h + (agg[srt]-h_head[end]) @ W^T + b) =================
__global__ __launch_bounds__(256) void layer_mfma(u16* __restrict__ h, const u16* __restrict__ h_head,
                                                  const float* __restrict__ agg, const u16* __restrict__ Wbf,
                                                  const float* __restrict__ b, const int* __restrict__ srt,
                                                  const int* __restrict__ endi){
  __shared__ u16 Alds[128][136];          // 34.8 KB
  const int t = threadIdx.x, lane = t & 63, wv = t >> 6;
  const int wr = wv >> 1, wc = wv & 1;
  const long e0 = (long)blockIdx.x * 128;

  bf16x8 bfrag[4][4];
  {
    const int jb = (lane & 15), kg = (lane >> 4)*8;
    #pragma unroll
    for (int fc = 0; fc < 4; ++fc)
      #pragma unroll
      for (int ks = 0; ks < 4; ++ks)
        bfrag[ks][fc] = *(const bf16x8*)&Wbf[(size_t)(wc*64 + fc*16 + jb)*128 + ks*32 + kg];
  }
  {
    const int rt = t >> 3, ct = (t & 7)*16;   // 8 threads/row, 16 cols each
    #pragma unroll
    for (int pass = 0; pass < 4; ++pass){
      const int r = pass*32 + rt;
      const long e = e0 + r;
      if (e < NE){
        const int s = srt[e], d = endi[e];
        const float* ap = &agg[(size_t)s*DH + ct];
        const u16*  hp = &h_head[(size_t)d*DH + ct];
        #pragma unroll
        for (int c4 = 0; c4 < 4; ++c4){
          float4 av = *(const float4*)&ap[c4*4];
          ushort4 hv = *(const ushort4*)&hp[c4*4];
          ushort4 o;
          o.x = f2bf(av.x - bf2f(hv.x));
          o.y = f2bf(av.y - bf2f(hv.y));
          o.z = f2bf(av.z - bf2f(hv.z));
          o.w = f2bf(av.w - bf2f(hv.w));
          *(ushort4*)&Alds[r][ct + c4*4] = o;
        }
      } else {
        ushort4 z; z.x=0; z.y=0; z.z=0; z.w=0;
        #pragma unroll
        for (int c4 = 0; c4 < 4; ++c4) *(ushort4*)&Alds[r][ct + c4*4] = z;
      }
    }
  }
  __syncthreads();

  f32x4 acc[4][4];
  #pragma unroll
  for (int fr = 0; fr < 4; ++fr)
    #pragma unroll
    for (int fc = 0; fc < 4; ++fc){ acc[fr][fc][0]=0.f; acc[fr][fc][1]=0.f; acc[fr][fc][2]=0.f; acc[fr][fc][3]=0.f; }
  const int ar = (lane & 15), akg = (lane >> 4)*8;
  #pragma unroll
  for (int ks = 0; ks < 4; ++ks){
    bf16x8 a[4];
    #pragma unroll
    for (int fr = 0; fr < 4; ++fr)
      a[fr] = *(const bf16x8*)&Alds[wr*64 + fr*16 + ar][ks*32 + akg];
    #pragma unroll
    for (int fr = 0; fr < 4; ++fr)
      #pragma unroll
      for (int fc = 0; fc < 4; ++fc)
        acc[fr][fc] = __builtin_amdgcn_mfma_f32_16x16x32_bf16(a[fr], bfrag[ks][fc], acc[fr][fc], 0, 0, 0);
  }

  float* Clds = (float*)&Alds[0][0];       // reuse as [64][132] f32 (33.8 KB <= 34.8 KB)
  const int cr0 = (lane >> 4)*4, cc = (lane & 15);
  for (int half = 0; half < 2; ++half){
    __syncthreads();
    if (wr == half){
      #pragma unroll
      for (int fr = 0; fr < 4; ++fr)
        #pragma unroll
        for (int fc = 0; fc < 4; ++fc)
          #pragma unroll
          for (int r = 0; r < 4; ++r)
            Clds[(fr*16 + cr0 + r)*132 + wc*64 + fc*16 + cc] = acc[fr][fc][r];
    }
    __syncthreads();
    const int rr = t >> 2, cb = (t & 3)*32;
    const long e = e0 + half*64 + rr;
    if (e < NE){
      u16* hp = &h[(size_t)e*DH + cb];
      #pragma unroll
      for (int c8 = 0; c8 < 4; ++c8){
        float4 c0 = *(const float4*)&Clds[rr*132 + cb + c8*8];
        float4 c1 = *(const float4*)&Clds[rr*132 + cb + c8*8 + 4];
        float4 b0 = *(const float4*)&b[cb + c8*8];
        float4 b1 = *(const float4*)&b[cb + c8*8 + 4];
        ushort4 o0 = *(const ushort4*)&hp[c8*8];
        ushort4 o1 = *(const ushort4*)&hp[c8*8 + 4];
        ushort4 n0, n1;
        n0.x = f2bf(lrelu(c0.x + b0.x + bf2f(o0.x)));
        n0.y = f2bf(lrelu(c0.y + b0.y + bf2f(o0.y)));
        n0.z = f2bf(lrelu(c0.z + b0.z + bf2f(o0.z)));
        n0.w = f2bf(lrelu(c0.w + b0.w + bf2f(o0.w)));
        n1.x = f2bf(lrelu(c1.x + b1.x + bf2f(o1.x)));
        n1.y = f2bf(lrelu(c1.y + b1.y + bf2f(o1.y)));
        n1.z = f2bf(lrelu(c1.z + b1.z + bf2f(o1.z)));
        n1.w = f2bf(lrelu(c1.w + b1.w + bf2f(o1.w)));
        *(ushort4*)&hp[c8*8] = n0; *(ushort4*)&hp[c8*8+4] = n1;
      }
    }
  }
}

// ================= nodes: atom = lrelu(hnode @ Wmol^T + b); normed = atom/||atom|| =================
__global__ __launch_bounds__(256) void node_kernel(
    const float* __restrict__ hn, const float* __restrict__ W,
    const float* __restrict__ b, float* __restrict__ atom, float* __restrict__ normed)
{
  __shared__ float Wt[64*132];
  __shared__ float ms[32*DH];
  const int t = threadIdx.x;
  const int r0 = blockIdx.x * 32;
  const int jg = t & 31, eg = t >> 5;
  for (int idx = t; idx < 32*DH; idx += 256) {
    const int r = r0 + (idx >> 7);
    ms[idx] = (r < NN) ? hn[(size_t)r*DH + (idx & 127)] : 0.f;
  }
  float acc[4][4] = {};
  for (int c = 0; c < 2; ++c) {
    __syncthreads();
    for (int idx = t; idx < 128*64; idx += 256) {
      const int j = idx >> 6, kl = idx & 63;
      Wt[kl*132 + j] = W[j*DH + c*64 + kl];
    }
    __syncthreads();
    #pragma unroll 4
    for (int kl = 0; kl < 64; ++kl) {
      const float4 w = *(const float4*)&Wt[kl*132 + jg*4];
      const int kg = c*64 + kl;
      #pragma unroll
      for (int i = 0; i < 4; ++i) {
        const float mv = ms[(eg*4+i)*DH + kg];
        acc[i][0] += mv*w.x; acc[i][1] += mv*w.y; acc[i][2] += mv*w.z; acc[i][3] += mv*w.w;
      }
    }
  }
  float bj[4];
  #pragma unroll
  for (int c2 = 0; c2 < 4; ++c2) bj[c2] = b[jg*4 + c2];
  #pragma unroll
  for (int i = 0; i < 4; ++i) {
    const int r = r0 + eg*4 + i;
    float v[4]; float ss = 0.f;
    #pragma unroll
    for (int c2 = 0; c2 < 4; ++c2) { v[c2] = lrelu(acc[i][c2] + bj[c2]); ss += v[c2]*v[c2]; }
    ss += __shfl_xor(ss, 1); ss += __shfl_xor(ss, 2); ss += __shfl_xor(ss, 4);
    ss += __shfl_xor(ss, 8); ss += __shfl_xor(ss, 16);
    if (r < NN) {
      *(float4*)&atom[(size_t)r*DH + jg*4] = make_float4(v[0],v[1],v[2],v[3]);
      const float inv = 1.f / fmaxf(sqrtf(ss), 1e-12f);
      *(float4*)&normed[(size_t)r*DH + jg*4] = make_float4(v[0]*inv,v[1]*inv,v[2]*inv,v[3]*inv);
    }
  }
}

// ================= per-graph sum (batch sorted -> contiguous ranges) + out GEMV =================
__global__ __launch_bounds__(128) void graph_out_kernel(const float* __restrict__ normed, const int* __restrict__ batch,
                                                        const float* __restrict__ Wo, const float* __restrict__ bo,
                                                        float* __restrict__ out){
  const int g = blockIdx.x, t = threadIdx.x;
  int lo, hi;
  { int a=0, bb=NN; while(a<bb){ int m=(a+bb)>>1; if (batch[m] < g) a=m+1; else bb=m; } lo=a; }
  { int a=lo, bb=NN; while(a<bb){ int m=(a+bb)>>1; if (batch[m] < g+1) a=m+1; else bb=m; } hi=a; }
  float s = 0.f;
  for (int n = lo; n < hi; ++n) s += normed[(size_t)n*DH + t];
  float v = s * Wo[t];
  #pragma unroll
  for (int d2 = 1; d2 < 64; d2 <<= 1) v += __shfl_xor(v, d2);
  __shared__ float red[2];
  if ((t & 63) == 0) red[t >> 6] = v;
  __syncthreads();
  if (t == 0) out[g] = red[0] + red[1] + bo[0];
}

extern "C" void kernel_launch(void* const* d_in, const int* in_sizes, int n_in,
                              void* d_out, int out_size, void* d_ws, size_t ws_size,
                              hipStream_t stream)
{
  const float* cf     = (const float*)d_in[1];
  const int*   srt    = (const int*)d_in[2];
  const int*   endi   = (const int*)d_in[3];
  const int*   batch  = (const int*)d_in[5];
  const float* W_init = (const float*)d_in[6];
  const float* b_init = (const float*)d_in[7];
  const float* W_h1   = (const float*)d_in[8];
  const float* b_h1   = (const float*)d_in[9];
  const float* W_mol  = (const float*)d_in[10];
  const float* b_mol  = (const float*)d_in[11];
  const float* W_out  = (const float*)d_in[12];
  const float* b_out  = (const float*)d_in[13];

  float* out  = (float*)d_out;
  float* atom = out + NG;

  char* ws = (char*)d_ws;
  u16*   h      = (u16*)(ws);                    // 256,000,000 B
  u16*   h_head = (u16*)(ws + 256000000);        // 12,800,000 B
  float* agg    = (float*)(ws + 268800000);      // 25,600,000 B
  float* hnode  = (float*)(ws + 294400000);      // 25,600,000 B
  int*   listE  = (int*)(ws + 320000000);        // 4,000,000 B
  int*   listS  = (int*)(ws + 324000000);        // 4,000,000 B
  int*   offE   = (int*)(ws + 328000000);        // 200,704 B (50176 ints)
  int*   offS   = (int*)(ws + 328200704);        // 200,704 B
  int*   curE   = (int*)(ws + 328401408);        // 200,704 B
  int*   curS   = (int*)(ws + 328602112);        // 200,704 B
  u16*   Wbf1   = (u16*)(ws + 328802816);        // 32,768 B
  u16*   Wbf0   = (u16*)(ws + 328835584);        // 40,960 B
  float* normed = (float*)(ws);                  // reuse h region (h dead by then)

  // ---- CSR build (int atomics only)
  hipMemsetAsync(curE, 0, 200704, stream);
  hipMemsetAsync(curS, 0, 200704, stream);
  hist_kernel<<<1024, 256, 0, stream>>>(endi, srt, curE, curS);
  scan_kernel<<<1, 1024, 0, stream>>>(curE, offE);
  scan_kernel<<<1, 1024, 0, stream>>>(curS, offS);
  hipMemcpyAsync(curE, offE, (size_t)NN*4, hipMemcpyDeviceToDevice, stream);
  hipMemcpyAsync(curS, offS, (size_t)NN*4, hipMemcpyDeviceToDevice, stream);
  scatter_kernel<<<1024, 256, 0, stream>>>(endi, srt, curE, curS, listE, listS);
  convertW_kernel<<<80, 256, 0, stream>>>(W_h1, W_init, Wbf1, Wbf0);

  // ---- layer 0
  layer0_mfma<<<(NE + 127)/128, 256, 0, stream>>>(cf, Wbf0, b_init, h);

  // ---- layers 1..3 (gather agg, snapshot head rows, fused MFMA layer)
  for (int l = 0; l < 3; ++l){
    gather_kernel<<<NN/4, 256, 0, stream>>>(h, listE, offE, agg);
    hipMemcpyAsync(h_head, h, (size_t)NN*DH*2, hipMemcpyDeviceToDevice, stream);
    layer_mfma<<<(NE + 127)/128, 256, 0, stream>>>(h, h_head, agg, Wbf1, b_h1, srt, endi);
  }

  // ---- h_node = segment_sum(h3, srt), then node MLP + normalize, then per-graph sum + out
  gather_kernel<<<NN/4, 256, 0, stream>>>(h, listS, offS, hnode);
  node_kernel<<<(NN + 31)/32, 256, 0, stream>>>(hnode, W_mol, b_mol, atom, normed);
  graph_out_kernel<<<NG, 128, 0, stream>>>(normed, batch, W_out, b_out, out);
}

// Round 3
// 1444.879 us; speedup vs baseline: 4.9469x; 1.2946x over previous
//
#include <hip/hip_runtime.h>

#define NN 50000
#define NE 1000000
#define NG 1000
#define KE 147
#define DH 128

using u16 = unsigned short;
typedef __attribute__((ext_vector_type(8))) short bf16x8;
typedef __attribute__((ext_vector_type(4))) float f32x4;

__device__ __forceinline__ float lrelu(float v){ return fmaxf(v, 0.01f*v); }
__device__ __forceinline__ float bf2f(u16 u){ unsigned int x = ((unsigned int)u)<<16; float f; __builtin_memcpy(&f,&x,4); return f; }
__device__ __forceinline__ u16 f2bf(float f){ unsigned int x; __builtin_memcpy(&x,&f,4); x += 0x7fffu + ((x>>16)&1u); return (u16)(x>>16); }

// ================= CSR build =================
__global__ __launch_bounds__(256) void hist_kernel(const int* __restrict__ endi, const int* __restrict__ srt,
                                                   int* __restrict__ cntE, int* __restrict__ cntS){
  for (int i = blockIdx.x*256 + threadIdx.x; i < NE; i += gridDim.x*256){
    atomicAdd(&cntE[endi[i]], 1);
    atomicAdd(&cntS[srt[i]], 1);
  }
}

__global__ __launch_bounds__(1024) void scan_kernel(const int* __restrict__ deg, int* __restrict__ off){
  __shared__ int wsum[17];
  const int t = threadIdx.x, lane = t & 63, wv = t >> 6;
  int carry = 0;
  for (int base = 0; base < 50176; base += 1024){
    const int i = base + t;
    int v = (i < NN) ? deg[i] : 0;
    int s = v;
    #pragma unroll
    for (int d = 1; d < 64; d <<= 1){
      int x = __shfl_up(s, d);
      if (lane >= d) s += x;
    }
    if (lane == 63) wsum[wv] = s;
    __syncthreads();
    if (t == 0){
      int run = 0;
      #pragma unroll
      for (int k = 0; k < 16; ++k){ int x = wsum[k]; wsum[k] = run; run += x; }
      wsum[16] = run;
    }
    __syncthreads();
    if (i <= NN) off[i] = carry + wsum[wv] + s - v;   // exclusive scan; off[NN] = total
    carry += wsum[16];
    __syncthreads();
  }
}

__global__ __launch_bounds__(256) void scatter_kernel(const int* __restrict__ endi, const int* __restrict__ srt,
                                                      int* __restrict__ curE, int* __restrict__ curS,
                                                      int* __restrict__ listE, int* __restrict__ listS){
  for (int i = blockIdx.x*256 + threadIdx.x; i < NE; i += gridDim.x*256){
    int p = atomicAdd(&curE[endi[i]], 1); listE[p] = i;
    int q = atomicAdd(&curS[srt[i]], 1);  listS[q] = i;
  }
}

__global__ __launch_bounds__(256) void convertW_kernel(const float* __restrict__ W1, const float* __restrict__ W0,
                                                       u16* __restrict__ Wbf1, u16* __restrict__ Wbf0){
  int i = blockIdx.x*256 + threadIdx.x;
  if (i < 128*128) Wbf1[i] = f2bf(W1[i]);
  if (i < 128*160){
    int j = i/160, k = i - j*160;
    Wbf0[i] = (k < KE) ? f2bf(W0[j*KE + k]) : (u16)0;
  }
}

// ================= segment-sum via CSR gather (one wave per node) =================
__global__ __launch_bounds__(256) void gather_kernel(const u16* __restrict__ h, const int* __restrict__ list,
                                                     const int* __restrict__ off, float* __restrict__ out){
  const int t = threadIdx.x, lane = t & 63, wv = t >> 6;
  const int node = blockIdx.x*4 + wv;
  if (node >= NN) return;
  const int lo = off[node], hi = off[node+1];
  float2 acc = make_float2(0.f, 0.f);
  const int c = lane*2;
  int j = lo;
  for (; j + 4 <= hi; j += 4){
    int e0 = list[j], e1 = list[j+1], e2 = list[j+2], e3 = list[j+3];
    ushort2 p0 = *(const ushort2*)&h[(size_t)e0*DH + c];
    ushort2 p1 = *(const ushort2*)&h[(size_t)e1*DH + c];
    ushort2 p2 = *(const ushort2*)&h[(size_t)e2*DH + c];
    ushort2 p3 = *(const ushort2*)&h[(size_t)e3*DH + c];
    acc.x += bf2f(p0.x)+bf2f(p1.x)+bf2f(p2.x)+bf2f(p3.x);
    acc.y += bf2f(p0.y)+bf2f(p1.y)+bf2f(p2.y)+bf2f(p3.y);
  }
  for (; j < hi; ++j){
    int e = list[j];
    ushort2 p = *(const ushort2*)&h[(size_t)e*DH + c];
    acc.x += bf2f(p.x); acc.y += bf2f(p.y);
  }
  *(float2*)&out[(size_t)node*DH + c] = acc;
}

// ================= layer 0: h = lrelu(cf @ W0^T + b), MFMA, flat f32 LDS staging =================
__global__ __launch_bounds__(256) void layer0_mfma(const float* __restrict__ cf, const u16* __restrict__ Wbf0,
                                                   const float* __restrict__ b, u16* __restrict__ h){
  __shared__ __align__(16) float Af[128*148];   // 75,776 B; row stride 148 f32 (592B: 16B-aligned, 2-way banks)
  const int t = threadIdx.x, lane = t & 63, wv = t >> 6;
  const int wr = wv >> 1, wc = wv & 1;
  const long e0 = (long)blockIdx.x * 128;

  bf16x8 bfrag[5][4];
  const int jb = lane & 15, kg8 = (lane >> 4)*8;
  #pragma unroll
  for (int fc = 0; fc < 4; ++fc)
    #pragma unroll
    for (int ks = 0; ks < 5; ++ks)
      bfrag[ks][fc] = *(const bf16x8*)&Wbf0[(size_t)(wc*64 + fc*16 + jb)*160 + ks*32 + kg8];

  const long gbase = e0 * KE;
  if (e0 + 128 <= NE){
    for (int i = t; i < 128*KE; i += 256){
      int r = i / KE, cc2 = i - r*KE;
      Af[r*148 + cc2] = cf[gbase + i];
    }
  } else {
    for (int i = t; i < 128*148; i += 256) Af[i] = 0.f;
    __syncthreads();
    for (int i = t; i < 128*KE; i += 256){
      long g = gbase + i;
      if (g < (long)NE*KE){ int r = i / KE, cc2 = i - r*KE; Af[r*148 + cc2] = cf[g]; }
    }
  }
  __syncthreads();

  f32x4 acc[4][4];
  #pragma unroll
  for (int fr = 0; fr < 4; ++fr)
    #pragma unroll
    for (int fc = 0; fc < 4; ++fc){ acc[fr][fc][0]=0.f; acc[fr][fc][1]=0.f; acc[fr][fc][2]=0.f; acc[fr][fc][3]=0.f; }
  const int ar = lane & 15;
  #pragma unroll
  for (int ks = 0; ks < 5; ++ks){
    const int k0 = ks*32 + kg8;
    bf16x8 a[4];
    #pragma unroll
    for (int fr = 0; fr < 4; ++fr){
      const float* rp = &Af[(wr*64 + fr*16 + ar)*148];
      float v[8];
      if (k0 + 8 <= KE){
        float4 x = *(const float4*)&rp[k0];
        float4 y = *(const float4*)&rp[k0+4];
        v[0]=x.x; v[1]=x.y; v[2]=x.z; v[3]=x.w; v[4]=y.x; v[5]=y.y; v[6]=y.z; v[7]=y.w;
      } else {
        #pragma unroll
        for (int q = 0; q < 8; ++q) v[q] = (k0+q < KE) ? rp[k0+q] : 0.f;
      }
      u16 tmp[8];
      #pragma unroll
      for (int q = 0; q < 8; ++q) tmp[q] = f2bf(v[q]);
      a[fr] = *(const bf16x8*)tmp;
    }
    #pragma unroll
    for (int fr = 0; fr < 4; ++fr)
      #pragma unroll
      for (int fc = 0; fc < 4; ++fc)
        acc[fr][fc] = __builtin_amdgcn_mfma_f32_16x16x32_bf16(a[fr], bfrag[ks][fc], acc[fr][fc], 0, 0, 0);
  }

  float* Clds = (float*)Af;                 // reuse as [64][132] f32
  const int cr0 = (lane >> 4)*4, cc = (lane & 15);
  for (int half = 0; half < 2; ++half){
    __syncthreads();
    if (wr == half){
      #pragma unroll
      for (int fr = 0; fr < 4; ++fr)
        #pragma unroll
        for (int fc = 0; fc < 4; ++fc)
          #pragma unroll
          for (int r = 0; r < 4; ++r)
            Clds[(fr*16 + cr0 + r)*132 + wc*64 + fc*16 + cc] = acc[fr][fc][r];
    }
    __syncthreads();
    const int rr = t >> 2, cb = (t & 3)*32;
    const long e = e0 + half*64 + rr;
    if (e < NE){
      u16* hp = &h[(size_t)e*DH + cb];
      #pragma unroll
      for (int c8 = 0; c8 < 4; ++c8){
        float4 c0 = *(const float4*)&Clds[rr*132 + cb + c8*8];
        float4 c1 = *(const float4*)&Clds[rr*132 + cb + c8*8 + 4];
        float4 b0 = *(const float4*)&b[cb + c8*8];
        float4 b1 = *(const float4*)&b[cb + c8*8 + 4];
        ushort4 n0, n1;
        n0.x = f2bf(lrelu(c0.x + b0.x)); n0.y = f2bf(lrelu(c0.y + b0.y));
        n0.z = f2bf(lrelu(c0.z + b0.z)); n0.w = f2bf(lrelu(c0.w + b0.w));
        n1.x = f2bf(lrelu(c1.x + b1.x)); n1.y = f2bf(lrelu(c1.y + b1.y));
        n1.z = f2bf(lrelu(c1.z + b1.z)); n1.w = f2bf(lrelu(c1.w + b1.w));
        *(ushort4*)&hp[c8*8] = n0; *(ushort4*)&hp[c8*8+4] = n1;
      }
    }
  }
}

// ================= P/Q tiny GEMM: rows 0..N-1: P = agg@W^T + b ; rows N..2N-1: Q = h[0:N]@W^T =================
__global__ __launch_bounds__(256) void pq_gemm(const float* __restrict__ agg, const u16* __restrict__ h,
                                               const u16* __restrict__ Wbf, const float* __restrict__ b,
                                               float* __restrict__ P, float* __restrict__ Q){
  __shared__ u16 Alds[128][136];
  const int t = threadIdx.x, lane = t & 63, wv = t >> 6;
  const int wr = wv >> 1, wc = wv & 1;
  const int r0 = blockIdx.x * 128;

  bf16x8 bfrag[4][4];
  const int jb = lane & 15, kg8 = (lane >> 4)*8;
  #pragma unroll
  for (int fc = 0; fc < 4; ++fc)
    #pragma unroll
    for (int ks = 0; ks < 4; ++ks)
      bfrag[ks][fc] = *(const bf16x8*)&Wbf[(size_t)(wc*64 + fc*16 + jb)*128 + ks*32 + kg8];

  {
    const int rt = t >> 1, half = t & 1;
    const int gr = r0 + rt;
    u16* dst = &Alds[rt][half*64];
    if (gr < NN){
      const float4* src = (const float4*)&agg[(size_t)gr*DH + half*64];
      #pragma unroll
      for (int q = 0; q < 16; ++q){
        float4 x = src[q];
        ushort4 o; o.x=f2bf(x.x); o.y=f2bf(x.y); o.z=f2bf(x.z); o.w=f2bf(x.w);
        *(ushort4*)&dst[q*4] = o;
      }
    } else if (gr < 2*NN){
      const ushort4* src = (const ushort4*)&h[(size_t)(gr-NN)*DH + half*64];
      #pragma unroll
      for (int q = 0; q < 16; ++q) *(ushort4*)&dst[q*4] = src[q];
    } else {
      ushort4 z; z.x=0; z.y=0; z.z=0; z.w=0;
      #pragma unroll
      for (int q = 0; q < 16; ++q) *(ushort4*)&dst[q*4] = z;
    }
  }
  __syncthreads();

  f32x4 acc[4][4];
  #pragma unroll
  for (int fr = 0; fr < 4; ++fr)
    #pragma unroll
    for (int fc = 0; fc < 4; ++fc){ acc[fr][fc][0]=0.f; acc[fr][fc][1]=0.f; acc[fr][fc][2]=0.f; acc[fr][fc][3]=0.f; }
  const int ar = lane & 15;
  #pragma unroll
  for (int ks = 0; ks < 4; ++ks){
    bf16x8 a[4];
    #pragma unroll
    for (int fr = 0; fr < 4; ++fr)
      a[fr] = *(const bf16x8*)&Alds[wr*64 + fr*16 + ar][ks*32 + kg8];
    #pragma unroll
    for (int fr = 0; fr < 4; ++fr)
      #pragma unroll
      for (int fc = 0; fc < 4; ++fc)
        acc[fr][fc] = __builtin_amdgcn_mfma_f32_16x16x32_bf16(a[fr], bfrag[ks][fc], acc[fr][fc], 0, 0, 0);
  }

  const int crow = (lane >> 4)*4, ccol = (lane & 15);
  #pragma unroll
  for (int fr = 0; fr < 4; ++fr){
    #pragma unroll
    for (int r = 0; r < 4; ++r){
      const int grow = r0 + wr*64 + fr*16 + crow + r;
      if (grow < NN){
        #pragma unroll
        for (int fc = 0; fc < 4; ++fc){
          const int col = wc*64 + fc*16 + ccol;
          P[(size_t)grow*DH + col] = acc[fr][fc][r] + b[col];
        }
      } else if (grow < 2*NN){
        #pragma unroll
        for (int fc = 0; fc < 4; ++fc){
          const int col = wc*64 + fc*16 + ccol;
          Q[(size_t)(grow-NN)*DH + col] = acc[fr][fc][r];
        }
      }
    }
  }
}

// ================= fused edge update + next-layer gather (one wave per node, endi-CSR) ===========
// h[e] = lrelu(h[e] + P[srt[e]] - Q[n]);  agg[n] = sum over e in listE(n) of h_new[e]
__global__ __launch_bounds__(256) void fused_layer(u16* __restrict__ h, const float* __restrict__ P,
                                                   const float* __restrict__ Q, const int* __restrict__ srt,
                                                   const int* __restrict__ list, const int* __restrict__ off,
                                                   float* __restrict__ agg){
  const int t = threadIdx.x, lane = t & 63, wv = t >> 6;
  const int n = blockIdx.x*4 + wv;
  if (n >= NN) return;
  const int lo = off[n], hi = off[n+1];
  const int c = lane*2;
  const float2 qv = *(const float2*)&Q[(size_t)n*DH + c];
  float2 acc = make_float2(0.f, 0.f);
  int j = lo;
  for (; j + 4 <= hi; j += 4){
    int e0 = list[j], e1 = list[j+1], e2 = list[j+2], e3 = list[j+3];
    int s0 = srt[e0], s1 = srt[e1], s2 = srt[e2], s3 = srt[e3];
    ushort2 h0 = *(const ushort2*)&h[(size_t)e0*DH + c];
    ushort2 h1 = *(const ushort2*)&h[(size_t)e1*DH + c];
    ushort2 h2 = *(const ushort2*)&h[(size_t)e2*DH + c];
    ushort2 h3 = *(const ushort2*)&h[(size_t)e3*DH + c];
    float2 p0 = *(const float2*)&P[(size_t)s0*DH + c];
    float2 p1 = *(const float2*)&P[(size_t)s1*DH + c];
    float2 p2 = *(const float2*)&P[(size_t)s2*DH + c];
    float2 p3 = *(const float2*)&P[(size_t)s3*DH + c];
    float v0x = lrelu(bf2f(h0.x) + p0.x - qv.x), v0y = lrelu(bf2f(h0.y) + p0.y - qv.y);
    float v1x = lrelu(bf2f(h1.x) + p1.x - qv.x), v1y = lrelu(bf2f(h1.y) + p1.y - qv.y);
    float v2x = lrelu(bf2f(h2.x) + p2.x - qv.x), v2y = lrelu(bf2f(h2.y) + p2.y - qv.y);
    float v3x = lrelu(bf2f(h3.x) + p3.x - qv.x), v3y = lrelu(bf2f(h3.y) + p3.y - qv.y);
    ushort2 o0; o0.x=f2bf(v0x); o0.y=f2bf(v0y); *(ushort2*)&h[(size_t)e0*DH + c] = o0;
    ushort2 o1; o1.x=f2bf(v1x); o1.y=f2bf(v1y); *(ushort2*)&h[(size_t)e1*DH + c] = o1;
    ushort2 o2; o2.x=f2bf(v2x); o2.y=f2bf(v2y); *(ushort2*)&h[(size_t)e2*DH + c] = o2;
    ushort2 o3; o3.x=f2bf(v3x); o3.y=f2bf(v3y); *(ushort2*)&h[(size_t)e3*DH + c] = o3;
    acc.x += v0x + v1x + v2x + v3x;
    acc.y += v0y + v1y + v2y + v3y;
  }
  for (; j < hi; ++j){
    int e = list[j];
    int s = srt[e];
    ushort2 hh = *(const ushort2*)&h[(size_t)e*DH + c];
    float2 pp = *(const float2*)&P[(size_t)s*DH + c];
    float vx = lrelu(bf2f(hh.x) + pp.x - qv.x), vy = lrelu(bf2f(hh.y) + pp.y - qv.y);
    ushort2 oo; oo.x=f2bf(vx); oo.y=f2bf(vy); *(ushort2*)&h[(size_t)e*DH + c] = oo;
    acc.x += vx; acc.y += vy;
  }
  *(float2*)&agg[(size_t)n*DH + c] = acc;
}

// ================= nodes: atom = lrelu(hnode @ Wmol^T + b); normed = atom/||atom|| =================
__global__ __launch_bounds__(256) void node_kernel(
    const float* __restrict__ hn, const float* __restrict__ W,
    const float* __restrict__ b, float* __restrict__ atom, float* __restrict__ normed)
{
  __shared__ float Wt[64*132];
  __shared__ float ms[32*DH];
  const int t = threadIdx.x;
  const int r0 = blockIdx.x * 32;
  const int jg = t & 31, eg = t >> 5;
  for (int idx = t; idx < 32*DH; idx += 256) {
    const int r = r0 + (idx >> 7);
    ms[idx] = (r < NN) ? hn[(size_t)r*DH + (idx & 127)] : 0.f;
  }
  float acc[4][4] = {};
  for (int c = 0; c < 2; ++c) {
    __syncthreads();
    for (int idx = t; idx < 128*64; idx += 256) {
      const int j = idx >> 6, kl = idx & 63;
      Wt[kl*132 + j] = W[j*DH + c*64 + kl];
    }
    __syncthreads();
    #pragma unroll 4
    for (int kl = 0; kl < 64; ++kl) {
      const float4 w = *(const float4*)&Wt[kl*132 + jg*4];
      const int kg = c*64 + kl;
      #pragma unroll
      for (int i = 0; i < 4; ++i) {
        const float mv = ms[(eg*4+i)*DH + kg];
        acc[i][0] += mv*w.x; acc[i][1] += mv*w.y; acc[i][2] += mv*w.z; acc[i][3] += mv*w.w;
      }
    }
  }
  float bj[4];
  #pragma unroll
  for (int c2 = 0; c2 < 4; ++c2) bj[c2] = b[jg*4 + c2];
  #pragma unroll
  for (int i = 0; i < 4; ++i) {
    const int r = r0 + eg*4 + i;
    float v[4]; float ss = 0.f;
    #pragma unroll
    for (int c2 = 0; c2 < 4; ++c2) { v[c2] = lrelu(acc[i][c2] + bj[c2]); ss += v[c2]*v[c2]; }
    ss += __shfl_xor(ss, 1); ss += __shfl_xor(ss, 2); ss += __shfl_xor(ss, 4);
    ss += __shfl_xor(ss, 8); ss += __shfl_xor(ss, 16);
    if (r < NN) {
      *(float4*)&atom[(size_t)r*DH + jg*4] = make_float4(v[0],v[1],v[2],v[3]);
      const float inv = 1.f / fmaxf(sqrtf(ss), 1e-12f);
      *(float4*)&normed[(size_t)r*DH + jg*4] = make_float4(v[0]*inv,v[1]*inv,v[2]*inv,v[3]*inv);
    }
  }
}

// ================= per-graph sum (batch sorted -> contiguous ranges) + out GEMV =================
__global__ __launch_bounds__(128) void graph_out_kernel(const float* __restrict__ normed, const int* __restrict__ batch,
                                                        const float* __restrict__ Wo, const float* __restrict__ bo,
                                                        float* __restrict__ out){
  const int g = blockIdx.x, t = threadIdx.x;
  int lo, hi;
  { int a=0, bb=NN; while(a<bb){ int m=(a+bb)>>1; if (batch[m] < g) a=m+1; else bb=m; } lo=a; }
  { int a=lo, bb=NN; while(a<bb){ int m=(a+bb)>>1; if (batch[m] < g+1) a=m+1; else bb=m; } hi=a; }
  float s = 0.f;
  for (int n = lo; n < hi; ++n) s += normed[(size_t)n*DH + t];
  float v = s * Wo[t];
  #pragma unroll
  for (int d2 = 1; d2 < 64; d2 <<= 1) v += __shfl_xor(v, d2);
  __shared__ float red[2];
  if ((t & 63) == 0) red[t >> 6] = v;
  __syncthreads();
  if (t == 0) out[g] = red[0] + red[1] + bo[0];
}

extern "C" void kernel_launch(void* const* d_in, const int* in_sizes, int n_in,
                              void* d_out, int out_size, void* d_ws, size_t ws_size,
                              hipStream_t stream)
{
  const float* cf     = (const float*)d_in[1];
  const int*   srt    = (const int*)d_in[2];
  const int*   endi   = (const int*)d_in[3];
  const int*   batch  = (const int*)d_in[5];
  const float* W_init = (const float*)d_in[6];
  const float* b_init = (const float*)d_in[7];
  const float* W_h1   = (const float*)d_in[8];
  const float* b_h1   = (const float*)d_in[9];
  const float* W_mol  = (const float*)d_in[10];
  const float* b_mol  = (const float*)d_in[11];
  const float* W_out  = (const float*)d_in[12];
  const float* b_out  = (const float*)d_in[13];

  float* out  = (float*)d_out;
  float* atom = out + NG;

  char* ws = (char*)d_ws;
  u16*   h     = (u16*)(ws);                    // 256,000,000 B
  float* agg   = (float*)(ws + 256000000);      // 25,600,000 B
  float* P     = (float*)(ws + 281600000);      // 25,600,000 B
  float* Q     = (float*)(ws + 307200000);      // 25,600,000 B
  int*   listE = (int*)(ws + 332800000);        // 4,000,000 B
  int*   listS = (int*)(ws + 336800000);        // 4,000,000 B
  int*   offE  = (int*)(ws + 340800000);        // 200,704 B
  int*   offS  = (int*)(ws + 341000704);        // 200,704 B
  int*   curE  = (int*)(ws + 341201408);        // 200,704 B
  int*   curS  = (int*)(ws + 341402112);        // 200,704 B
  u16*   Wbf1  = (u16*)(ws + 341602816);        // 32,768 B
  u16*   Wbf0  = (u16*)(ws + 341635584);        // 40,960 B
  float* hnode = P;                             // reuse P after last fused pass
  float* normed = (float*)(ws);                 // reuse h region (h dead after gatherS)

  // ---- CSR build (int atomics only)
  hipMemsetAsync(curE, 0, 200704, stream);
  hipMemsetAsync(curS, 0, 200704, stream);
  hist_kernel<<<1024, 256, 0, stream>>>(endi, srt, curE, curS);
  scan_kernel<<<1, 1024, 0, stream>>>(curE, offE);
  scan_kernel<<<1, 1024, 0, stream>>>(curS, offS);
  hipMemcpyAsync(curE, offE, (size_t)NN*4, hipMemcpyDeviceToDevice, stream);
  hipMemcpyAsync(curS, offS, (size_t)NN*4, hipMemcpyDeviceToDevice, stream);
  scatter_kernel<<<1024, 256, 0, stream>>>(endi, srt, curE, curS, listE, listS);
  convertW_kernel<<<80, 256, 0, stream>>>(W_h1, W_init, Wbf1, Wbf0);

  // ---- layer 0
  layer0_mfma<<<(NE + 127)/128, 256, 0, stream>>>(cf, Wbf0, b_init, h);
  gather_kernel<<<NN/4, 256, 0, stream>>>(h, listE, offE, agg);

  // ---- layers 1..3: tiny P/Q GEMMs + fused elementwise update + gather
  for (int l = 0; l < 3; ++l){
    pq_gemm<<<(2*NN + 127)/128, 256, 0, stream>>>(agg, h, Wbf1, b_h1, P, Q);
    fused_layer<<<NN/4, 256, 0, stream>>>(h, P, Q, srt, listE, offE, agg);
  }

  // ---- h_node = segment_sum(h3, srt), node MLP + normalize, per-graph sum + out
  gather_kernel<<<NN/4, 256, 0, stream>>>(h, listS, offS, hnode);
  node_kernel<<<(NN + 31)/32, 256, 0, stream>>>(hnode, W_mol, b_mol, atom, normed);
  graph_out_kernel<<<NG, 128, 0, stream>>>(normed, batch, W_out, b_out, out);
}

// Round 4
// 1291.327 us; speedup vs baseline: 5.5351x; 1.1189x over previous
//
#include <hip/hip_runtime.h>

#define NN 50000
#define NE 1000000
#define NG 1000
#define KE 147
#define DH 128

using u16 = unsigned short;
typedef __attribute__((ext_vector_type(8))) short bf16x8;
typedef __attribute__((ext_vector_type(4))) float f32x4;

__device__ __forceinline__ float lrelu(float v){ return fmaxf(v, 0.01f*v); }
__device__ __forceinline__ float bf2f(u16 u){ unsigned int x = ((unsigned int)u)<<16; float f; __builtin_memcpy(&f,&x,4); return f; }
__device__ __forceinline__ u16 f2bf(float f){ unsigned int x; __builtin_memcpy(&x,&f,4); x += 0x7fffu + ((x>>16)&1u); return (u16)(x>>16); }

// ================= CSR build =================
__global__ __launch_bounds__(256) void hist_kernel(const int* __restrict__ endi, const int* __restrict__ srt,
                                                   int* __restrict__ cntE, int* __restrict__ cntS){
  for (int i = blockIdx.x*256 + threadIdx.x; i < NE; i += gridDim.x*256){
    atomicAdd(&cntE[endi[i]], 1);
    atomicAdd(&cntS[srt[i]], 1);
  }
}

__global__ __launch_bounds__(1024) void scan2_kernel(const int* __restrict__ cntE, int* __restrict__ offE,
                                                     const int* __restrict__ cntS, int* __restrict__ offS){
  const int* deg = blockIdx.x ? cntS : cntE;
  int* off = blockIdx.x ? offS : offE;
  __shared__ int wsum[17];
  const int t = threadIdx.x, lane = t & 63, wv = t >> 6;
  int carry = 0;
  for (int base = 0; base < 50176; base += 1024){
    const int i = base + t;
    int v = (i < NN) ? deg[i] : 0;
    int s = v;
    #pragma unroll
    for (int d = 1; d < 64; d <<= 1){
      int x = __shfl_up(s, d);
      if (lane >= d) s += x;
    }
    if (lane == 63) wsum[wv] = s;
    __syncthreads();
    if (t == 0){
      int run = 0;
      #pragma unroll
      for (int k = 0; k < 16; ++k){ int x = wsum[k]; wsum[k] = run; run += x; }
      wsum[16] = run;
    }
    __syncthreads();
    if (i <= NN) off[i] = carry + wsum[wv] + s - v;
    carry += wsum[16];
    __syncthreads();
  }
}

// scatter: build rankE (edge -> permuted row), srtE (per permuted row), listS/endS (srt-CSR)
__global__ __launch_bounds__(256) void scatter_kernel(const int* __restrict__ endi, const int* __restrict__ srt,
                                                      int* __restrict__ curE, int* __restrict__ curS,
                                                      int* __restrict__ rankE, int* __restrict__ srtE,
                                                      int* __restrict__ listS, int* __restrict__ endS){
  for (int i = blockIdx.x*256 + threadIdx.x; i < NE; i += gridDim.x*256){
    const int e = endi[i], s = srt[i];
    int p = atomicAdd(&curE[e], 1);
    rankE[i] = p; srtE[p] = s;
    int q = atomicAdd(&curS[s], 1);
    listS[q] = i; endS[q] = e;
  }
}

__global__ __launch_bounds__(256) void post_kernel(const int* __restrict__ listS, const int* __restrict__ rankE,
                                                   int* __restrict__ listS2){
  for (int i = blockIdx.x*256 + threadIdx.x; i < NE; i += gridDim.x*256)
    listS2[i] = rankE[listS[i]];
}

__global__ __launch_bounds__(256) void convertW_kernel(const float* __restrict__ W1, const float* __restrict__ W0,
                                                       u16* __restrict__ Wbf1, u16* __restrict__ Wbf0){
  int i = blockIdx.x*256 + threadIdx.x;
  if (i < 128*128) Wbf1[i] = f2bf(W1[i]);
  if (i < 128*160){
    int j = i/160, k = i - j*160;
    Wbf0[i] = (k < KE) ? f2bf(W0[j*KE + k]) : (u16)0;
  }
}

// ================= layer 0: h'[rankE[e]] = lrelu(cf[e] @ W0^T + b), bf16 LDS staging =================
__global__ __launch_bounds__(256) void layer0_mfma(const float* __restrict__ cf, const u16* __restrict__ Wbf0,
                                                   const float* __restrict__ b, const int* __restrict__ rankE,
                                                   u16* __restrict__ h){
  __shared__ __align__(16) u16 As[128*168];   // 43,008 B; stride 168 u16 = 84 dw (2-way banks)
  const int t = threadIdx.x, lane = t & 63, wv = t >> 6;
  const int wr = wv >> 1, wc = wv & 1;
  const long e0 = (long)blockIdx.x * 128;

  bf16x8 bfrag[5][4];
  const int jb = lane & 15, kg8 = (lane >> 4)*8;
  #pragma unroll
  for (int fc = 0; fc < 4; ++fc)
    #pragma unroll
    for (int ks = 0; ks < 5; ++ks)
      bfrag[ks][fc] = *(const bf16x8*)&Wbf0[(size_t)(wc*64 + fc*16 + jb)*160 + ks*32 + kg8];

  const long gbase = e0 * KE;
  if (e0 + 128 <= NE){
    for (int i = t; i < 128*KE; i += 256){
      int r = i / KE, c = i - r*KE;
      As[r*168 + c] = f2bf(cf[gbase + i]);
    }
  } else {
    for (int i = t; i < 128*168; i += 256) As[i] = 0;
    __syncthreads();
    for (int i = t; i < 128*KE; i += 256){
      long g = gbase + i;
      if (g < (long)NE*KE){ int r = i / KE, c = i - r*KE; As[r*168 + c] = f2bf(cf[g]); }
    }
  }
  // zero pad cols 147..159 (read by ks=4)
  for (int i = t; i < 128*13; i += 256){
    int r = i / 13, c = i - r*13;
    As[r*168 + 147 + c] = 0;
  }
  __syncthreads();

  f32x4 acc[4][4];
  #pragma unroll
  for (int fr = 0; fr < 4; ++fr)
    #pragma unroll
    for (int fc = 0; fc < 4; ++fc){ acc[fr][fc][0]=0.f; acc[fr][fc][1]=0.f; acc[fr][fc][2]=0.f; acc[fr][fc][3]=0.f; }
  const int ar = lane & 15;
  #pragma unroll
  for (int ks = 0; ks < 5; ++ks){
    bf16x8 a[4];
    #pragma unroll
    for (int fr = 0; fr < 4; ++fr)
      a[fr] = *(const bf16x8*)&As[(wr*64 + fr*16 + ar)*168 + ks*32 + kg8];
    #pragma unroll
    for (int fr = 0; fr < 4; ++fr)
      #pragma unroll
      for (int fc = 0; fc < 4; ++fc)
        acc[fr][fc] = __builtin_amdgcn_mfma_f32_16x16x32_bf16(a[fr], bfrag[ks][fc], acc[fr][fc], 0, 0, 0);
  }

  float* Clds = (float*)As;                 // reuse as [64][132] f32 (33.8 KB)
  const int cr0 = (lane >> 4)*4, cc = lane & 15;
  for (int half = 0; half < 2; ++half){
    __syncthreads();
    if (wr == half){
      #pragma unroll
      for (int fr = 0; fr < 4; ++fr)
        #pragma unroll
        for (int fc = 0; fc < 4; ++fc)
          #pragma unroll
          for (int r = 0; r < 4; ++r)
            Clds[(fr*16 + cr0 + r)*132 + wc*64 + fc*16 + cc] = acc[fr][fc][r];
    }
    __syncthreads();
    const int rr = t & 63, cw = t >> 6;     // row per lane, 32-col quarter per wave
    const long e = e0 + half*64 + rr;
    if (e < NE){
      const int orow = rankE[e];
      u16* hp = &h[(size_t)orow*DH + cw*32];
      #pragma unroll
      for (int c8 = 0; c8 < 4; ++c8){
        float4 c0v = *(const float4*)&Clds[rr*132 + cw*32 + c8*8];
        float4 c1v = *(const float4*)&Clds[rr*132 + cw*32 + c8*8 + 4];
        float4 b0 = *(const float4*)&b[cw*32 + c8*8];
        float4 b1 = *(const float4*)&b[cw*32 + c8*8 + 4];
        ushort4 n0, n1;
        n0.x = f2bf(lrelu(c0v.x + b0.x)); n0.y = f2bf(lrelu(c0v.y + b0.y));
        n0.z = f2bf(lrelu(c0v.z + b0.z)); n0.w = f2bf(lrelu(c0v.w + b0.w));
        n1.x = f2bf(lrelu(c1v.x + b1.x)); n1.y = f2bf(lrelu(c1v.y + b1.y));
        n1.z = f2bf(lrelu(c1v.z + b1.z)); n1.w = f2bf(lrelu(c1v.w + b1.w));
        *(ushort4*)&hp[c8*8] = n0; *(ushort4*)&hp[c8*8+4] = n1;
      }
    }
  }
}

// ================= agg[n] = sum of h' rows [offE[n], offE[n+1]) — sequential =================
__global__ __launch_bounds__(256) void aggE_kernel(const u16* __restrict__ h, const int* __restrict__ off,
                                                   float* __restrict__ agg){
  const int t = threadIdx.x, lane = t & 63, wv = t >> 6;
  const int n = blockIdx.x*4 + wv;
  if (n >= NN) return;
  const int lo = off[n], hi = off[n+1];
  const int c4 = (lane & 31)*4, sub = lane >> 5;
  float a0=0.f, a1=0.f, a2=0.f, a3=0.f;
  for (int i = lo + sub; i < hi; i += 2){
    ushort4 hv = *(const ushort4*)&h[(size_t)i*DH + c4];
    a0 += bf2f(hv.x); a1 += bf2f(hv.y); a2 += bf2f(hv.z); a3 += bf2f(hv.w);
  }
  a0 += __shfl_xor(a0, 32); a1 += __shfl_xor(a1, 32);
  a2 += __shfl_xor(a2, 32); a3 += __shfl_xor(a3, 32);
  if (sub == 0) *(float4*)&agg[(size_t)n*DH + c4] = make_float4(a0,a1,a2,a3);
}

// ================= P/Q GEMM: P = agg@W^T + b ; Q = h'[rankE[0:N]]@W^T =================
__global__ __launch_bounds__(256) void pq_gemm(const float* __restrict__ agg, const u16* __restrict__ h,
                                               const int* __restrict__ rankE, const u16* __restrict__ Wbf,
                                               const float* __restrict__ b, float* __restrict__ P,
                                               float* __restrict__ Q){
  __shared__ u16 Alds[128][136];
  const int t = threadIdx.x, lane = t & 63, wv = t >> 6;
  const int wr = wv >> 1, wc = wv & 1;
  const int r0 = blockIdx.x * 128;

  bf16x8 bfrag[4][4];
  const int jb = lane & 15, kg8 = (lane >> 4)*8;
  #pragma unroll
  for (int fc = 0; fc < 4; ++fc)
    #pragma unroll
    for (int ks = 0; ks < 4; ++ks)
      bfrag[ks][fc] = *(const bf16x8*)&Wbf[(size_t)(wc*64 + fc*16 + jb)*128 + ks*32 + kg8];

  {
    const int rt = t >> 1, half = t & 1;
    const int gr = r0 + rt;
    u16* dst = &Alds[rt][half*64];
    if (gr < NN){
      const float4* src = (const float4*)&agg[(size_t)gr*DH + half*64];
      #pragma unroll
      for (int q = 0; q < 16; ++q){
        float4 x = src[q];
        ushort4 o; o.x=f2bf(x.x); o.y=f2bf(x.y); o.z=f2bf(x.z); o.w=f2bf(x.w);
        *(ushort4*)&dst[q*4] = o;
      }
    } else if (gr < 2*NN){
      const int row = rankE[gr - NN];
      const ushort4* src = (const ushort4*)&h[(size_t)row*DH + half*64];
      #pragma unroll
      for (int q = 0; q < 16; ++q) *(ushort4*)&dst[q*4] = src[q];
    } else {
      ushort4 z; z.x=0; z.y=0; z.z=0; z.w=0;
      #pragma unroll
      for (int q = 0; q < 16; ++q) *(ushort4*)&dst[q*4] = z;
    }
  }
  __syncthreads();

  f32x4 acc[4][4];
  #pragma unroll
  for (int fr = 0; fr < 4; ++fr)
    #pragma unroll
    for (int fc = 0; fc < 4; ++fc){ acc[fr][fc][0]=0.f; acc[fr][fc][1]=0.f; acc[fr][fc][2]=0.f; acc[fr][fc][3]=0.f; }
  const int ar = lane & 15;
  #pragma unroll
  for (int ks = 0; ks < 4; ++ks){
    bf16x8 a[4];
    #pragma unroll
    for (int fr = 0; fr < 4; ++fr)
      a[fr] = *(const bf16x8*)&Alds[wr*64 + fr*16 + ar][ks*32 + kg8];
    #pragma unroll
    for (int fr = 0; fr < 4; ++fr)
      #pragma unroll
      for (int fc = 0; fc < 4; ++fc)
        acc[fr][fc] = __builtin_amdgcn_mfma_f32_16x16x32_bf16(a[fr], bfrag[ks][fc], acc[fr][fc], 0, 0, 0);
  }

  const int crow = (lane >> 4)*4, ccol = lane & 15;
  #pragma unroll
  for (int fr = 0; fr < 4; ++fr){
    #pragma unroll
    for (int r = 0; r < 4; ++r){
      const int grow = r0 + wr*64 + fr*16 + crow + r;
      if (grow < NN){
        #pragma unroll
        for (int fc = 0; fc < 4; ++fc){
          const int col = wc*64 + fc*16 + ccol;
          P[(size_t)grow*DH + col] = acc[fr][fc][r] + b[col];
        }
      } else if (grow < 2*NN){
        #pragma unroll
        for (int fc = 0; fc < 4; ++fc){
          const int col = wc*64 + fc*16 + ccol;
          Q[(size_t)(grow-NN)*DH + col] = acc[fr][fc][r];
        }
      }
    }
  }
}

// ===== middle layers: h'[i] = lrelu(h'[i] + P[srtE[i]] - Q[n]) for i in [offE[n],offE[n+1]); agg[n]=sum =====
__global__ __launch_bounds__(256) void fused_mid(u16* __restrict__ h, const float* __restrict__ P,
                                                 const float* __restrict__ Q, const int* __restrict__ srtE,
                                                 const int* __restrict__ off, float* __restrict__ agg){
  const int t = threadIdx.x, lane = t & 63, wv = t >> 6;
  const int n = blockIdx.x*4 + wv;
  if (n >= NN) return;
  const int lo = off[n], hi = off[n+1];
  const int c4 = (lane & 31)*4, sub = lane >> 5;
  const float4 qv = *(const float4*)&Q[(size_t)n*DH + c4];
  float a0=0.f, a1=0.f, a2=0.f, a3=0.f;
  for (int i = lo + sub; i < hi; i += 2){
    const int s = srtE[i];
    ushort4 hv = *(const ushort4*)&h[(size_t)i*DH + c4];
    float4 pv = *(const float4*)&P[(size_t)s*DH + c4];
    float v0 = lrelu(bf2f(hv.x) + pv.x - qv.x);
    float v1 = lrelu(bf2f(hv.y) + pv.y - qv.y);
    float v2 = lrelu(bf2f(hv.z) + pv.z - qv.z);
    float v3 = lrelu(bf2f(hv.w) + pv.w - qv.w);
    ushort4 o; o.x=f2bf(v0); o.y=f2bf(v1); o.z=f2bf(v2); o.w=f2bf(v3);
    *(ushort4*)&h[(size_t)i*DH + c4] = o;
    a0 += v0; a1 += v1; a2 += v2; a3 += v3;
  }
  a0 += __shfl_xor(a0, 32); a1 += __shfl_xor(a1, 32);
  a2 += __shfl_xor(a2, 32); a3 += __shfl_xor(a3, 32);
  if (sub == 0) *(float4*)&agg[(size_t)n*DH + c4] = make_float4(a0,a1,a2,a3);
}

// ===== last layer: hnode[s] = sum over srt-CSR of lrelu(h'[listS2[i]] + P[s] - Q[endS[i]]) =====
__global__ __launch_bounds__(256) void fused_last(const u16* __restrict__ h, const float* __restrict__ P,
                                                  const float* __restrict__ Q, const int* __restrict__ endS,
                                                  const int* __restrict__ listS2, const int* __restrict__ off,
                                                  float* __restrict__ hnode){
  const int t = threadIdx.x, lane = t & 63, wv = t >> 6;
  const int s = blockIdx.x*4 + wv;
  if (s >= NN) return;
  const int lo = off[s], hi = off[s+1];
  const int c4 = (lane & 31)*4, sub = lane >> 5;
  const float4 pv = *(const float4*)&P[(size_t)s*DH + c4];
  float a0=0.f, a1=0.f, a2=0.f, a3=0.f;
  for (int i = lo + sub; i < hi; i += 2){
    const int row = listS2[i];
    const int d = endS[i];
    ushort4 hv = *(const ushort4*)&h[(size_t)row*DH + c4];
    float4 qv = *(const float4*)&Q[(size_t)d*DH + c4];
    a0 += lrelu(bf2f(hv.x) + pv.x - qv.x);
    a1 += lrelu(bf2f(hv.y) + pv.y - qv.y);
    a2 += lrelu(bf2f(hv.z) + pv.z - qv.z);
    a3 += lrelu(bf2f(hv.w) + pv.w - qv.w);
  }
  a0 += __shfl_xor(a0, 32); a1 += __shfl_xor(a1, 32);
  a2 += __shfl_xor(a2, 32); a3 += __shfl_xor(a3, 32);
  if (sub == 0) *(float4*)&hnode[(size_t)s*DH + c4] = make_float4(a0,a1,a2,a3);
}

// ================= nodes: atom = lrelu(hnode @ Wmol^T + b); normed = atom/||atom|| =================
__global__ __launch_bounds__(256) void node_kernel(
    const float* __restrict__ hn, const float* __restrict__ W,
    const float* __restrict__ b, float* __restrict__ atom, float* __restrict__ normed)
{
  __shared__ float Wt[64*132];
  __shared__ float ms[32*DH];
  const int t = threadIdx.x;
  const int r0 = blockIdx.x * 32;
  const int jg = t & 31, eg = t >> 5;
  for (int idx = t; idx < 32*DH; idx += 256) {
    const int r = r0 + (idx >> 7);
    ms[idx] = (r < NN) ? hn[(size_t)r*DH + (idx & 127)] : 0.f;
  }
  float acc[4][4] = {};
  for (int c = 0; c < 2; ++c) {
    __syncthreads();
    for (int idx = t; idx < 128*64; idx += 256) {
      const int j = idx >> 6, kl = idx & 63;
      Wt[kl*132 + j] = W[j*DH + c*64 + kl];
    }
    __syncthreads();
    #pragma unroll 4
    for (int kl = 0; kl < 64; ++kl) {
      const float4 w = *(const float4*)&Wt[kl*132 + jg*4];
      const int kg = c*64 + kl;
      #pragma unroll
      for (int i = 0; i < 4; ++i) {
        const float mv = ms[(eg*4+i)*DH + kg];
        acc[i][0] += mv*w.x; acc[i][1] += mv*w.y; acc[i][2] += mv*w.z; acc[i][3] += mv*w.w;
      }
    }
  }
  float bj[4];
  #pragma unroll
  for (int c2 = 0; c2 < 4; ++c2) bj[c2] = b[jg*4 + c2];
  #pragma unroll
  for (int i = 0; i < 4; ++i) {
    const int r = r0 + eg*4 + i;
    float v[4]; float ss = 0.f;
    #pragma unroll
    for (int c2 = 0; c2 < 4; ++c2) { v[c2] = lrelu(acc[i][c2] + bj[c2]); ss += v[c2]*v[c2]; }
    ss += __shfl_xor(ss, 1); ss += __shfl_xor(ss, 2); ss += __shfl_xor(ss, 4);
    ss += __shfl_xor(ss, 8); ss += __shfl_xor(ss, 16);
    if (r < NN) {
      *(float4*)&atom[(size_t)r*DH + jg*4] = make_float4(v[0],v[1],v[2],v[3]);
      const float inv = 1.f / fmaxf(sqrtf(ss), 1e-12f);
      *(float4*)&normed[(size_t)r*DH + jg*4] = make_float4(v[0]*inv,v[1]*inv,v[2]*inv,v[3]*inv);
    }
  }
}

// ================= per-graph sum + out GEMV =================
__global__ __launch_bounds__(128) void graph_out_kernel(const float* __restrict__ normed, const int* __restrict__ batch,
                                                        const float* __restrict__ Wo, const float* __restrict__ bo,
                                                        float* __restrict__ out){
  const int g = blockIdx.x, t = threadIdx.x;
  int lo, hi;
  { int a=0, bb=NN; while(a<bb){ int m=(a+bb)>>1; if (batch[m] < g) a=m+1; else bb=m; } lo=a; }
  { int a=lo, bb=NN; while(a<bb){ int m=(a+bb)>>1; if (batch[m] < g+1) a=m+1; else bb=m; } hi=a; }
  float s = 0.f;
  for (int n = lo; n < hi; ++n) s += normed[(size_t)n*DH + t];
  float v = s * Wo[t];
  #pragma unroll
  for (int d2 = 1; d2 < 64; d2 <<= 1) v += __shfl_xor(v, d2);
  __shared__ float red[2];
  if ((t & 63) == 0) red[t >> 6] = v;
  __syncthreads();
  if (t == 0) out[g] = red[0] + red[1] + bo[0];
}

extern "C" void kernel_launch(void* const* d_in, const int* in_sizes, int n_in,
                              void* d_out, int out_size, void* d_ws, size_t ws_size,
                              hipStream_t stream)
{
  const float* cf     = (const float*)d_in[1];
  const int*   srt    = (const int*)d_in[2];
  const int*   endi   = (const int*)d_in[3];
  const int*   batch  = (const int*)d_in[5];
  const float* W_init = (const float*)d_in[6];
  const float* b_init = (const float*)d_in[7];
  const float* W_h1   = (const float*)d_in[8];
  const float* b_h1   = (const float*)d_in[9];
  const float* W_mol  = (const float*)d_in[10];
  const float* b_mol  = (const float*)d_in[11];
  const float* W_out  = (const float*)d_in[12];
  const float* b_out  = (const float*)d_in[13];

  float* out  = (float*)d_out;
  float* atom = out + NG;

  char* ws = (char*)d_ws;
  u16*   h      = (u16*)(ws);                    // 256,000,000 B (end-CSR permuted rows)
  float* agg    = (float*)(ws + 256000000);      // 25,600,000 B
  float* P      = (float*)(ws + 281600000);      // 25,600,000 B
  float* Q      = (float*)(ws + 307200000);      // 25,600,000 B
  int*   srtE   = (int*)(ws + 332800000);        // 4,000,000 B
  int*   listS  = (int*)(ws + 336800000);        // 4,000,000 B
  int*   endS   = (int*)(ws + 340800000);        // 4,000,000 B
  int*   rankE  = (int*)(ws + 344800000);        // 4,000,000 B
  int*   listS2 = (int*)(ws + 348800000);        // 4,000,000 B
  int*   offE   = (int*)(ws + 352800000);        // 200,704 B
  int*   offS   = (int*)(ws + 353000704);        // 200,704 B
  int*   curE   = (int*)(ws + 353201408);        // 200,704 B
  int*   curS   = (int*)(ws + 353402112);        // 200,704 B
  u16*   Wbf1   = (u16*)(ws + 353602816);        // 32,768 B
  u16*   Wbf0   = (u16*)(ws + 353635584);        // 40,960 B
  float* hnode  = agg;                           // agg dead after last pq_gemm
  float* normed = (float*)(ws);                  // reuse h region (h dead after fused_last)

  // ---- CSR build (int atomics only)
  hipMemsetAsync(curE, 0, 200704, stream);
  hipMemsetAsync(curS, 0, 200704, stream);
  hist_kernel<<<1024, 256, 0, stream>>>(endi, srt, curE, curS);
  scan2_kernel<<<2, 1024, 0, stream>>>(curE, offE, curS, offS);
  hipMemcpyAsync(curE, offE, (size_t)NN*4, hipMemcpyDeviceToDevice, stream);
  hipMemcpyAsync(curS, offS, (size_t)NN*4, hipMemcpyDeviceToDevice, stream);
  scatter_kernel<<<1024, 256, 0, stream>>>(endi, srt, curE, curS, rankE, srtE, listS, endS);
  post_kernel<<<1024, 256, 0, stream>>>(listS, rankE, listS2);
  convertW_kernel<<<80, 256, 0, stream>>>(W_h1, W_init, Wbf1, Wbf0);

  // ---- layer 0 (writes h in end-CSR order)
  layer0_mfma<<<(NE + 127)/128, 256, 0, stream>>>(cf, Wbf0, b_init, rankE, h);
  aggE_kernel<<<NN/4, 256, 0, stream>>>(h, offE, agg);

  // ---- layers 1..2: tiny P/Q GEMMs + fused sequential update producing next agg
  for (int l = 0; l < 2; ++l){
    pq_gemm<<<(2*NN + 127)/128, 256, 0, stream>>>(agg, h, rankE, Wbf1, b_h1, P, Q);
    fused_mid<<<NN/4, 256, 0, stream>>>(h, P, Q, srtE, offE, agg);
  }
  // ---- layer 3: P/Q then direct hnode accumulation (no h write, no separate gather)
  pq_gemm<<<(2*NN + 127)/128, 256, 0, stream>>>(agg, h, rankE, Wbf1, b_h1, P, Q);
  fused_last<<<NN/4, 256, 0, stream>>>(h, P, Q, endS, listS2, offS, hnode);

  // ---- node MLP + normalize, per-graph sum + out
  node_kernel<<<(NN + 31)/32, 256, 0, stream>>>(hnode, W_mol, b_mol, atom, normed);
  graph_out_kernel<<<NG, 128, 0, stream>>>(normed, batch, W_out, b_out, out);
}